// Round 3
// baseline (1099.764 us; speedup 1.0000x reference)
//
#include <hip/hip_runtime.h>
#include <hip/hip_bf16.h>

typedef __bf16 bf16;
typedef float f32x4 __attribute__((ext_vector_type(4)));
typedef bf16 bf16x8 __attribute__((ext_vector_type(8)));
typedef bf16 bf16x4 __attribute__((ext_vector_type(4)));

#define E_TOT 400000
#define TE 64          // edges per block (4 waves x 16 edges, independent)

// ---------------------------------------------------------------------------
// exact GELU (final layer only): A&S 7.1.26 erf, |err|<=1.5e-7.
// ---------------------------------------------------------------------------
__device__ __forceinline__ float gelu_exact(float x){
  float z = fabsf(x) * 0.70710678118654752f;
  float t = __builtin_amdgcn_rcpf(__builtin_fmaf(0.3275911f, z, 1.0f));
  float p = __builtin_fmaf(1.061405429f, t, -1.453152027f);
  p = __builtin_fmaf(p, t, 1.421413741f);
  p = __builtin_fmaf(p, t, -0.284496736f);
  p = __builtin_fmaf(p, t, 0.254829592f);
  p = p * t;
  float ex = __expf(-z * z);
  float er = __builtin_fmaf(-p, ex, 1.0f);
  er = copysignf(er, x);
  return 0.5f * x * (1.0f + er);
}

// ---------------------------------------------------------------------------
// fast GELU (hidden layers, bf16-masked): tanh form.
// ---------------------------------------------------------------------------
__device__ __forceinline__ float gelu_fast(float x){
  float x2 = x * x;
  float y  = x * __builtin_fmaf(0.07135482f, x2, 1.5957691216f);
  float e  = __expf(y);
  float r  = __builtin_amdgcn_rcpf(e + 1.0f);
  return __builtin_fmaf(-x, r, x);
}

// ---------------------------------------------------------------------------
// G = feature_emb @ feature_emb.T  (64x64, fp32 in / fp32 out)
// ---------------------------------------------------------------------------
__global__ void compute_g(const float* __restrict__ fe, float* __restrict__ Gm){
  const int a = blockIdx.x, f = threadIdx.x;
  const float4* ra = (const float4*)(fe + a * 256);
  const float4* rf = (const float4*)(fe + f * 256);
  float s = 0.f;
  for (int h = 0; h < 64; ++h){
    float4 x = ra[h];
    float4 y = rf[h];
    s += x.x * y.x + x.y * y.y + x.z * y.z + x.w * y.w;
  }
  Gm[a * 64 + f] = s;
}

// ---------------------------------------------------------------------------
// Pre-swizzle fp32 weight W [Kd][Md] into bf16 MFMA A-operand fragments:
// frag t=(kt*Mtiles+mtg), lane L, elem j = W[kt*32 + (L>>4)*8 + j][mtg*16 + (L&15)]
// ---------------------------------------------------------------------------
__global__ void swizzle_w(const float* __restrict__ src, bf16* __restrict__ dst,
                          int Kd, int Md){
  const int t = blockIdx.x;
  const int L = threadIdx.x;            // 64
  const int Mtiles = Md >> 4;
  const int kt = t / Mtiles, mtg = t % Mtiles;
  const int k0 = kt * 32 + (L >> 4) * 8;
  const int m  = mtg * 16 + (L & 15);
  bf16x8 v;
  #pragma unroll
  for (int j = 0; j < 8; ++j) v[j] = (bf16)src[(k0 + j) * Md + m];
  *(bf16x8*)&dst[((size_t)t * 64 + L) * 8] = v;
}

// ---------------------------------------------------------------------------
// Per-wave GEMM, e-tile = 1 (the wave's 16 edges), full m-range:
//   acc[mt] initialized from global bias (C-in = bias), then
//   acc[mt] += W^T[m-tile mt][k] * ACT[e][k] over KT k-tiles.
// B operand from wave-private swizzled LDS rows; A from pre-swizzled global
// (L2-resident).  One b128 B-read feeds MT MFMAs.
// ---------------------------------------------------------------------------
template<int KT, int MT>
__device__ __forceinline__ void mfma_gemm(const bf16* __restrict__ Wz,
                                          const bf16* __restrict__ Sw,
                                          const float* __restrict__ bias,
                                          int lane, f32x4 (&acc)[MT])
{
  const int l16 = lane & 15, quad = lane >> 4;
  #pragma unroll
  for (int mt = 0; mt < MT; ++mt)
    acc[mt] = *(const f32x4*)&bias[mt * 16 + quad * 4];
  #pragma unroll
  for (int kt = 0; kt < KT; ++kt){
    const int col = (kt * 32 + quad * 8) ^ ((l16 & 7) << 3);
    const bf16x8 b = *(const bf16x8*)&Sw[l16 * 256 + col];
    #pragma unroll
    for (int mt = 0; mt < MT; ++mt){
      const bf16x8 a = *(const bf16x8*)&Wz[(size_t)((kt * MT + mt) * 64 + lane) * 8];
      acc[mt] = __builtin_amdgcn_mfma_f32_16x16x32_bf16(a, b, acc[mt], 0, 0, 0);
    }
  }
}

// ---------------------------------------------------------------------------
// Fused main kernel: 64 edges/block, 256 threads = 4 INDEPENDENT waves.
// Each wave owns 16 edges end-to-end; zero __syncthreads (all LDS hazards are
// same-wave, ordered by data dependence).  LDS = 4*16*512B = 32768B exactly
// -> 5 blocks/CU (20 waves).  Activation rows are XOR-swizzled
// (col ^= (row&7)<<3, elem units) instead of padded: bank-balanced for the
// b128 reads / b64 writes / b128 stage-0 writes.
// ---------------------------------------------------------------------------
__global__ __launch_bounds__(256, 5) void fused_attr_net(
    const float* __restrict__ km,        // [100000,64]
    const int*   __restrict__ obs_idx,   // [E]
    const int*   __restrict__ omi_idx,   // [E]
    const int*   __restrict__ ai_idx,    // [E]
    const float* __restrict__ obs_embs,  // [100000,256]
    const float* __restrict__ b1g, const float* __restrict__ b2g,
    const float* __restrict__ rrbg, const float* __restrict__ rcbg,
    const float* __restrict__ Gm,        // [64,64] fp32
    const bf16* __restrict__ W1s, const bf16* __restrict__ W2s,
    const bf16* __restrict__ RRs, const bf16* __restrict__ RCs,
    float* __restrict__ out)
{
  __shared__ __align__(16) bf16 S_[4 * 16 * 256];   // 32768 B

  const int tid  = threadIdx.x;
  const int e0   = blockIdx.x * TE;
  const int lane = tid & 63;
  const int w    = tid >> 6;
  const int l16  = lane & 15;
  const int quad = lane >> 4;
  const int swz  = (l16 & 7) << 3;      // element-unit XOR swizzle for row l16

  bf16* Sw = S_ + w * 16 * 256;         // wave-private 16 rows x 256

  const int myedge = e0 + w * 16 + l16;
  const int aiv = ai_idx[myedge];       // for GEMM2 epilogue (Gm row)
  const int oiv = obs_idx[myedge];      // for GEMM3 epilogue (obs_embs row)

  // ---- stage 0: SM = softmax(known_mask[omi] * (1-eye)[ai]) -> Sw rows
  {
    const int eL = lane >> 2, part = lane & 3;    // 4 lanes x 16 feats per edge
    const int edge = e0 + w * 16 + eL;
    const int omi = omi_idx[edge];
    const int ai  = ai_idx[edge];
    const float4* kr = (const float4*)(km + omi * 64 + part * 16);
    float s[16]; float cnt = 0.f;
    #pragma unroll
    for (int q = 0; q < 4; ++q){
      const float4 v4 = kr[q];
      const float vv[4] = {v4.x, v4.y, v4.z, v4.w};
      #pragma unroll
      for (int j = 0; j < 4; ++j){
        const int f = part * 16 + q * 4 + j;
        const float v = (f == ai) ? 0.f : vv[j];
        s[q * 4 + j] = v; cnt += v;
      }
    }
    cnt += __shfl_xor(cnt, 1);
    cnt += __shfl_xor(cnt, 2);
    // s in {0,1}: sum(exp) = cnt*e + (64-cnt)
    const float denom = __builtin_fmaf(cnt, 1.7182818284590452f, 64.0f);
    const float p0 = __builtin_amdgcn_rcpf(denom);
    const float d10 = 1.7182818284590452f * p0;   // p1 - p0
    bf16x8 o0, o1;
    #pragma unroll
    for (int j = 0; j < 8; ++j) o0[j] = (bf16)__builtin_fmaf(s[j],     d10, p0);
    #pragma unroll
    for (int j = 0; j < 8; ++j) o1[j] = (bf16)__builtin_fmaf(s[8 + j], d10, p0);
    const int sw = (eL & 7) << 3;
    *(bf16x8*)&Sw[eL * 256 + ((part * 16)     ^ sw)] = o0;
    *(bf16x8*)&Sw[eL * 256 + ((part * 16 + 8) ^ sw)] = o1;
  }
  // no barrier: each wave reads only its own rows from here on

  f32x4 acc[16];

  // ---- GEMM1: H1 = gelu(SM @ W1 + b1)  [16e x 256] -> Sw
  mfma_gemm<2, 16>(W1s, Sw, b1g, lane, acc);
  #pragma unroll
  for (int mt = 0; mt < 16; ++mt){
    const int c = (mt * 16 + quad * 4) ^ swz;
    bf16x4 o;
    o[0] = (bf16)gelu_fast(acc[mt][0]);
    o[1] = (bf16)gelu_fast(acc[mt][1]);
    o[2] = (bf16)gelu_fast(acc[mt][2]);
    o[3] = (bf16)gelu_fast(acc[mt][3]);
    *(bf16x4*)&Sw[l16 * 256 + c] = o;
  }

  // ---- GEMM2: R = gelu(H1 @ W2 + b2) * G[ai]  [16e x 64] -> Sw cols 0..63
  {
    f32x4 acc2[4];
    mfma_gemm<8, 4>(W2s, Sw, b2g, lane, acc2);
    #pragma unroll
    for (int mt = 0; mt < 4; ++mt){
      const int m0 = mt * 16 + quad * 4;
      const float4 g = *(const float4*)&Gm[aiv * 64 + m0];
      bf16x4 o;
      o[0] = (bf16)(gelu_fast(acc2[mt][0]) * g.x);
      o[1] = (bf16)(gelu_fast(acc2[mt][1]) * g.y);
      o[2] = (bf16)(gelu_fast(acc2[mt][2]) * g.z);
      o[3] = (bf16)(gelu_fast(acc2[mt][3]) * g.w);
      *(bf16x4*)&Sw[l16 * 256 + (m0 ^ swz)] = o;
    }
  }

  // ---- GEMM3: P = gelu(R @ rrW + rrb) * obs_embs[oi]  [16e x 256] -> Sw
  mfma_gemm<2, 16>(RRs, Sw, rrbg, lane, acc);
  #pragma unroll
  for (int mt = 0; mt < 16; ++mt){
    const int m0 = mt * 16 + quad * 4;
    const float4 oh = *(const float4*)&obs_embs[(size_t)oiv * 256 + m0];
    bf16x4 o;
    o[0] = (bf16)(gelu_fast(acc[mt][0]) * oh.x);
    o[1] = (bf16)(gelu_fast(acc[mt][1]) * oh.y);
    o[2] = (bf16)(gelu_fast(acc[mt][2]) * oh.z);
    o[3] = (bf16)(gelu_fast(acc[mt][3]) * oh.w);
    *(bf16x4*)&Sw[l16 * 256 + (m0 ^ swz)] = o;
  }

  // ---- GEMM4: OUT = gelu(P @ rcW + rcb) -> direct fp32 global store
  mfma_gemm<8, 16>(RCs, Sw, rcbg, lane, acc);
  #pragma unroll
  for (int mt = 0; mt < 16; ++mt){
    const int m0 = mt * 16 + quad * 4;
    float4 o;
    o.x = gelu_exact(acc[mt][0]);
    o.y = gelu_exact(acc[mt][1]);
    o.z = gelu_exact(acc[mt][2]);
    o.w = gelu_exact(acc[mt][3]);
    *(float4*)&out[(size_t)myedge * 256 + m0] = o;
  }
}

// ---------------------------------------------------------------------------
extern "C" void kernel_launch(void* const* d_in, const int* in_sizes, int n_in,
                              void* d_out, int out_size, void* d_ws, size_t ws_size,
                              hipStream_t stream){
  const float* km   = (const float*)d_in[0];
  const int*   obsi = (const int*)d_in[1];
  const int*   omi  = (const int*)d_in[2];
  const int*   ai   = (const int*)d_in[3];
  const float* obs  = (const float*)d_in[4];
  const float* fe   = (const float*)d_in[5];
  const float* W1   = (const float*)d_in[6];
  const float* b1   = (const float*)d_in[7];
  const float* W2   = (const float*)d_in[8];
  const float* b2   = (const float*)d_in[9];
  const float* rrW  = (const float*)d_in[10];
  const float* rrb  = (const float*)d_in[11];
  const float* rcW  = (const float*)d_in[12];
  const float* rcb  = (const float*)d_in[13];
  float* out = (float*)d_out;

  char* ws = (char*)d_ws;
  float* Gm  = (float*)ws;                     // 16384 B
  bf16* W1s  = (bf16*)(ws + 16384);            // 32768 B
  bf16* W2s  = (bf16*)(ws + 49152);            // 32768 B
  bf16* RRs  = (bf16*)(ws + 81920);            // 32768 B
  bf16* RCs  = (bf16*)(ws + 114688);           // 131072 B  (total 245760 B)

  compute_g<<<dim3(64), dim3(64), 0, stream>>>(fe, Gm);
  swizzle_w<<<dim3(32),  dim3(64), 0, stream>>>(W1,  W1s, 64,  256);
  swizzle_w<<<dim3(32),  dim3(64), 0, stream>>>(W2,  W2s, 256, 64);
  swizzle_w<<<dim3(32),  dim3(64), 0, stream>>>(rrW, RRs, 64,  256);
  swizzle_w<<<dim3(128), dim3(64), 0, stream>>>(rcW, RCs, 256, 256);
  fused_attr_net<<<dim3(E_TOT / TE), dim3(256), 0, stream>>>(
      km, obsi, omi, ai, obs, b1, b2, rrb, rcb, Gm, W1s, W2s, RRs, RCs, out);
}

// Round 4
// 745.044 us; speedup vs baseline: 1.4761x; 1.4761x over previous
//
#include <hip/hip_runtime.h>
#include <hip/hip_bf16.h>

typedef __bf16 bf16;
typedef float f32x4 __attribute__((ext_vector_type(4)));
typedef bf16 bf16x8 __attribute__((ext_vector_type(8)));
typedef bf16 bf16x4 __attribute__((ext_vector_type(4)));

#define E_TOT 400000
#define TE 64          // edges per block (two pipelined halves of 32)
#define SROW 264       // LDS activation row stride (bf16 elems), 256+8 pad

// ---------------------------------------------------------------------------
// exact GELU (final layer only): A&S 7.1.26 erf, |err|<=1.5e-7.
// ---------------------------------------------------------------------------
__device__ __forceinline__ float gelu_exact(float x){
  float z = fabsf(x) * 0.70710678118654752f;
  float t = __builtin_amdgcn_rcpf(__builtin_fmaf(0.3275911f, z, 1.0f));
  float p = __builtin_fmaf(1.061405429f, t, -1.453152027f);
  p = __builtin_fmaf(p, t, 1.421413741f);
  p = __builtin_fmaf(p, t, -0.284496736f);
  p = __builtin_fmaf(p, t, 0.254829592f);
  p = p * t;
  float ex = __expf(-z * z);
  float er = __builtin_fmaf(-p, ex, 1.0f);
  er = copysignf(er, x);
  return 0.5f * x * (1.0f + er);
}

// ---------------------------------------------------------------------------
// fast GELU (hidden layers, bf16-masked): tanh form.
// ---------------------------------------------------------------------------
__device__ __forceinline__ float gelu_fast(float x){
  float x2 = x * x;
  float y  = x * __builtin_fmaf(0.07135482f, x2, 1.5957691216f);
  float e  = __expf(y);
  float r  = __builtin_amdgcn_rcpf(e + 1.0f);
  return __builtin_fmaf(-x, r, x);
}

// ---------------------------------------------------------------------------
// G = feature_emb @ feature_emb.T  (64x64, fp32 in / fp32 out)
// ---------------------------------------------------------------------------
__global__ void compute_g(const float* __restrict__ fe, float* __restrict__ Gm){
  const int a = blockIdx.x, f = threadIdx.x;
  const float4* ra = (const float4*)(fe + a * 256);
  const float4* rf = (const float4*)(fe + f * 256);
  float s = 0.f;
  for (int h = 0; h < 64; ++h){
    float4 x = ra[h];
    float4 y = rf[h];
    s += x.x * y.x + x.y * y.y + x.z * y.z + x.w * y.w;
  }
  Gm[a * 64 + f] = s;
}

// ---------------------------------------------------------------------------
// Pre-swizzle fp32 weight W [Kd][Md] into bf16 MFMA A-operand fragments:
// frag t=(kt*Mtiles+mtg), lane L, elem j = W[kt*32+(L>>4)*8+j][mtg*16+(L&15)]
// ---------------------------------------------------------------------------
__global__ void swizzle_w(const float* __restrict__ src, bf16* __restrict__ dst,
                          int Kd, int Md){
  const int t = blockIdx.x;
  const int L = threadIdx.x;            // 64
  const int Mtiles = Md >> 4;
  const int kt = t / Mtiles, mtg = t % Mtiles;
  const int k0 = kt * 32 + (L >> 4) * 8;
  const int m  = mtg * 16 + (L & 15);
  bf16x8 v;
  #pragma unroll
  for (int j = 0; j < 8; ++j) v[j] = (bf16)src[(k0 + j) * Md + m];
  *(bf16x8*)&dst[((size_t)t * 64 + L) * 8] = v;
}

// ---------------------------------------------------------------------------
// Half-tile per-wave GEMM (32 edges = 2 e-tiles):
//   acc[mt][et] = bias (C-in), then += W^T * ACT over KT k-tiles.
// A from pre-swizzled global (L2-resident); B from LDS half-buffer.
// ---------------------------------------------------------------------------
template<int KT, int MT, int MTOT>
__device__ __forceinline__ void mfma_gemm2(const bf16* __restrict__ Wz,
                                           const bf16* __restrict__ Sh,
                                           const float4 (&binit)[MT],
                                           int w, int lane, f32x4 (&acc)[MT][2])
{
  const int l16 = lane & 15, quad = lane >> 4;
  #pragma unroll
  for (int mt = 0; mt < MT; ++mt)
    #pragma unroll
    for (int et = 0; et < 2; ++et)
      acc[mt][et] = f32x4{binit[mt].x, binit[mt].y, binit[mt].z, binit[mt].w};
  #pragma unroll
  for (int kt = 0; kt < KT; ++kt){
    bf16x8 b[2];
    #pragma unroll
    for (int et = 0; et < 2; ++et)
      b[et] = *(const bf16x8*)&Sh[(et * 16 + l16) * SROW + kt * 32 + quad * 8];
    #pragma unroll
    for (int mt = 0; mt < MT; ++mt){
      const bf16x8 a = *(const bf16x8*)&Wz[(size_t)((kt * MTOT + (w * MT + mt)) * 64 + lane) * 8];
      #pragma unroll
      for (int et = 0; et < 2; ++et)
        acc[mt][et] = __builtin_amdgcn_mfma_f32_16x16x32_bf16(a, b[et], acc[mt][et], 0, 0, 0);
    }
  }
}

// ---------------------------------------------------------------------------
// Fused main kernel: 64 edges/block, 256 threads (4 waves), TWO-HALF
// SOFTWARE PIPELINE: each phase runs epilogue(prev half) [VALU + ds_write]
// concurrently with MFMA(other half) [ds_read + L2 loads + MFMA] on disjoint
// LDS halves, one barrier per phase.  Overlaps the VALU and MFMA pipes that
// R2's serial chain left alternating.
// ---------------------------------------------------------------------------
__global__ __launch_bounds__(256, 4) void fused_attr_net(
    const float* __restrict__ km,        // [100000,64]
    const int*   __restrict__ obs_idx,   // [E]
    const int*   __restrict__ omi_idx,   // [E]
    const int*   __restrict__ ai_idx,    // [E]
    const float* __restrict__ obs_embs,  // [100000,256]
    const float* __restrict__ b1g, const float* __restrict__ b2g,
    const float* __restrict__ rrbg, const float* __restrict__ rcbg,
    const float* __restrict__ Gm,        // [64,64] fp32
    const bf16* __restrict__ W1s, const bf16* __restrict__ W2s,
    const bf16* __restrict__ RRs, const bf16* __restrict__ RCs,
    float* __restrict__ out)
{
  __shared__ __align__(16) bf16 S_[TE * SROW];   // 33792 B: SA=rows 0-31, SB=rows 32-63
  __shared__ int ai_s[TE];
  __shared__ int oi_s[TE];

  const int tid  = threadIdx.x;
  const int e0   = blockIdx.x * TE;
  const int lane = tid & 63;
  const int w    = tid >> 6;
  const int l16  = lane & 15;
  const int quad = lane >> 4;

  bf16* SA = S_;
  bf16* SB = S_ + 32 * SROW;

  if (tid < TE){
    ai_s[tid] = ai_idx[e0 + tid];
    oi_s[tid] = obs_idx[e0 + tid];
  }

  // ---- stage 0: SM = softmax(known_mask[omi] * (1-eye)[ai]) -> S_ rows 0-63
  {
    const int e = tid >> 2, part = tid & 3;      // 4 threads x 16 feats per edge
    const int omi = omi_idx[e0 + e];
    const int ai  = ai_idx[e0 + e];
    const float4* kr = (const float4*)(km + omi * 64 + part * 16);
    float s[16]; float cnt = 0.f;
    #pragma unroll
    for (int q = 0; q < 4; ++q){
      const float4 v4 = kr[q];
      const float vv[4] = {v4.x, v4.y, v4.z, v4.w};
      #pragma unroll
      for (int j = 0; j < 4; ++j){
        const int f = part * 16 + q * 4 + j;
        const float v = (f == ai) ? 0.f : vv[j];
        s[q * 4 + j] = v; cnt += v;
      }
    }
    cnt += __shfl_xor(cnt, 1);
    cnt += __shfl_xor(cnt, 2);
    // s in {0,1}: sum(exp) = cnt*e + (64-cnt)
    const float denom = __builtin_fmaf(cnt, 1.7182818284590452f, 64.0f);
    const float p0 = __builtin_amdgcn_rcpf(denom);
    const float d10 = 1.7182818284590452f * p0;   // p1 - p0
    bf16x8 o0, o1;
    #pragma unroll
    for (int j = 0; j < 8; ++j) o0[j] = (bf16)__builtin_fmaf(s[j],     d10, p0);
    #pragma unroll
    for (int j = 0; j < 8; ++j) o1[j] = (bf16)__builtin_fmaf(s[8 + j], d10, p0);
    *(bf16x8*)&S_[e * SROW + part * 16]     = o0;
    *(bf16x8*)&S_[e * SROW + part * 16 + 8] = o1;
  }
  __syncthreads();

  // epilogue helpers (half-local edge e = et*16+l16; hb = 0 or 32)
  auto epi_h1 = [&](f32x4 (&A)[4][2], bf16* Sh){
    #pragma unroll
    for (int mt = 0; mt < 4; ++mt){
      const int mbase = (w * 4 + mt) * 16 + quad * 4;
      #pragma unroll
      for (int et = 0; et < 2; ++et){
        const int e = et * 16 + l16;
        bf16x4 o;
        o[0] = (bf16)gelu_fast(A[mt][et][0]);
        o[1] = (bf16)gelu_fast(A[mt][et][1]);
        o[2] = (bf16)gelu_fast(A[mt][et][2]);
        o[3] = (bf16)gelu_fast(A[mt][et][3]);
        *(bf16x4*)&Sh[e * SROW + mbase] = o;
      }
    }
  };
  auto epi_r = [&](f32x4 (&A)[1][2], bf16* Sh, int hb){
    const int mbase = w * 16 + quad * 4;
    #pragma unroll
    for (int et = 0; et < 2; ++et){
      const int e = et * 16 + l16;
      const float4 g = *(const float4*)&Gm[ai_s[hb + e] * 64 + mbase];
      bf16x4 o;
      o[0] = (bf16)(gelu_fast(A[0][et][0]) * g.x);
      o[1] = (bf16)(gelu_fast(A[0][et][1]) * g.y);
      o[2] = (bf16)(gelu_fast(A[0][et][2]) * g.z);
      o[3] = (bf16)(gelu_fast(A[0][et][3]) * g.w);
      *(bf16x4*)&Sh[e * SROW + mbase] = o;
    }
  };
  auto epi_p = [&](f32x4 (&A)[4][2], bf16* Sh, int hb){
    #pragma unroll
    for (int mt = 0; mt < 4; ++mt){
      const int mbase = (w * 4 + mt) * 16 + quad * 4;
      #pragma unroll
      for (int et = 0; et < 2; ++et){
        const int e = et * 16 + l16;
        const float4 oh = *(const float4*)&obs_embs[(size_t)oi_s[hb + e] * 256 + mbase];
        bf16x4 o;
        o[0] = (bf16)(gelu_fast(A[mt][et][0]) * oh.x);
        o[1] = (bf16)(gelu_fast(A[mt][et][1]) * oh.y);
        o[2] = (bf16)(gelu_fast(A[mt][et][2]) * oh.z);
        o[3] = (bf16)(gelu_fast(A[mt][et][3]) * oh.w);
        *(bf16x4*)&Sh[e * SROW + mbase] = o;
      }
    }
  };
  auto epi_out = [&](f32x4 (&A)[4][2], int hb){
    #pragma unroll
    for (int mt = 0; mt < 4; ++mt){
      const int mbase = (w * 4 + mt) * 16 + quad * 4;
      #pragma unroll
      for (int et = 0; et < 2; ++et){
        const int e = et * 16 + l16;
        float4 o;
        o.x = gelu_exact(A[mt][et][0]);
        o.y = gelu_exact(A[mt][et][1]);
        o.z = gelu_exact(A[mt][et][2]);
        o.w = gelu_exact(A[mt][et][3]);
        *(float4*)&out[(size_t)(e0 + hb + e) * 256 + mbase] = o;
      }
    }
  };

  f32x4 X[4][2], Y[4][2];
  f32x4 X2[1][2], Y2[1][2];
  float4 b4[4], b21[1];

  // ---- pipeline ----
  // P1: G1(h0)
  #pragma unroll
  for (int mt = 0; mt < 4; ++mt)
    b4[mt] = *(const float4*)&b1g[(w * 4 + mt) * 16 + quad * 4];
  mfma_gemm2<2, 4, 16>(W1s, SA, b4, w, lane, X);
  __syncthreads();

  // P2: epi1(h0)->SA | G1(h1)
  epi_h1(X, SA);
  mfma_gemm2<2, 4, 16>(W1s, SB, b4, w, lane, Y);
  __syncthreads();

  // P3: epi1(h1)->SB | G2(h0)
  b21[0] = *(const float4*)&b2g[w * 16 + quad * 4];
  epi_h1(Y, SB);
  mfma_gemm2<8, 1, 4>(W2s, SA, b21, w, lane, X2);
  __syncthreads();

  // P4: epi2(h0)->SA | G2(h1)
  epi_r(X2, SA, 0);
  mfma_gemm2<8, 1, 4>(W2s, SB, b21, w, lane, Y2);
  __syncthreads();

  // P5: epi2(h1)->SB | G3(h0)
  #pragma unroll
  for (int mt = 0; mt < 4; ++mt)
    b4[mt] = *(const float4*)&rrbg[(w * 4 + mt) * 16 + quad * 4];
  epi_r(Y2, SB, 32);
  mfma_gemm2<2, 4, 16>(RRs, SA, b4, w, lane, X);
  __syncthreads();

  // P6: epi3(h0)->SA | G3(h1)
  epi_p(X, SA, 0);
  mfma_gemm2<2, 4, 16>(RRs, SB, b4, w, lane, Y);
  __syncthreads();

  // P7: epi3(h1)->SB | G4(h0)
  #pragma unroll
  for (int mt = 0; mt < 4; ++mt)
    b4[mt] = *(const float4*)&rcbg[(w * 4 + mt) * 16 + quad * 4];
  epi_p(Y, SB, 32);
  mfma_gemm2<8, 4, 16>(RCs, SA, b4, w, lane, X);
  __syncthreads();

  // P8: epi4(h0)->out | G4(h1)   (no LDS hazard -> no barrier)
  epi_out(X, 0);
  mfma_gemm2<8, 4, 16>(RCs, SB, b4, w, lane, Y);

  // P9: epi4(h1)->out
  epi_out(Y, 32);
}

// ---------------------------------------------------------------------------
extern "C" void kernel_launch(void* const* d_in, const int* in_sizes, int n_in,
                              void* d_out, int out_size, void* d_ws, size_t ws_size,
                              hipStream_t stream){
  const float* km   = (const float*)d_in[0];
  const int*   obsi = (const int*)d_in[1];
  const int*   omi  = (const int*)d_in[2];
  const int*   ai   = (const int*)d_in[3];
  const float* obs  = (const float*)d_in[4];
  const float* fe   = (const float*)d_in[5];
  const float* W1   = (const float*)d_in[6];
  const float* b1   = (const float*)d_in[7];
  const float* W2   = (const float*)d_in[8];
  const float* b2   = (const float*)d_in[9];
  const float* rrW  = (const float*)d_in[10];
  const float* rrb  = (const float*)d_in[11];
  const float* rcW  = (const float*)d_in[12];
  const float* rcb  = (const float*)d_in[13];
  float* out = (float*)d_out;

  char* ws = (char*)d_ws;
  float* Gm  = (float*)ws;                     // 16384 B
  bf16* W1s  = (bf16*)(ws + 16384);            // 32768 B
  bf16* W2s  = (bf16*)(ws + 49152);            // 32768 B
  bf16* RRs  = (bf16*)(ws + 81920);            // 32768 B
  bf16* RCs  = (bf16*)(ws + 114688);           // 131072 B  (total 245760 B)

  compute_g<<<dim3(64), dim3(64), 0, stream>>>(fe, Gm);
  swizzle_w<<<dim3(32),  dim3(64), 0, stream>>>(W1,  W1s, 64,  256);
  swizzle_w<<<dim3(32),  dim3(64), 0, stream>>>(W2,  W2s, 256, 64);
  swizzle_w<<<dim3(32),  dim3(64), 0, stream>>>(rrW, RRs, 64,  256);
  swizzle_w<<<dim3(128), dim3(64), 0, stream>>>(rcW, RCs, 256, 256);
  fused_attr_net<<<dim3(E_TOT / TE), dim3(256), 0, stream>>>(
      km, obsi, omi, ai, obs, b1, b2, rrb, rcb, Gm, W1s, W2s, RRs, RCs, out);
}